// Round 9
// baseline (128.650 us; speedup 1.0000x reference)
//
#include <hip/hip_runtime.h>

#define B_  8
#define TE_ 256
#define TD_ 128
#define HE_ 512

typedef __attribute__((ext_vector_type(8))) short short8v;
typedef __attribute__((ext_vector_type(4))) float f32x4;

// ---- gemm_fused: Cws[3072,512] = [enc;dec] @ (Wa|Ua), trunc-split 3-term bf16 ----
// grid 384 = nt(16) x mt(24), bid = nt*24+mt -> XCD = mt%8 (A rows L2-local).
// B-tile (32 cols, K=512, hi+lo) converted inline into 64 KB XOR-swizzled LDS.
// K-loop has ZERO barriers: B resident, A fp32 streamed + split in registers.
__global__ __launch_bounds__(512) void gemm_fused(
    const float* __restrict__ enc, const float* __restrict__ dec,
    const float* __restrict__ Wa, const float* __restrict__ Ua,
    float* __restrict__ C) {
  __shared__ short BT[2][32][512];    // exactly 64 KB
  const int bid = blockIdx.x;
  const int mt = bid % 24, nt = bid / 24;
  const int m0 = mt * 128, n0 = nt * 32;
  const float* Bsrc = (mt < 16) ? Wa : Ua;
  const float* Asrc = (mt < 16) ? enc + (size_t)m0 * 512
                                : dec + (size_t)(m0 - 2048) * 512;
  const int tid = threadIdx.x;
  // ---- prologue: stage + split B tile (coalesced read, b16 scatter write) ----
  {
    const int kr = tid >> 3;          // 0..63
    const int c4 = (tid & 7) * 4;     // col group
    for (int p = 0; p < 8; ++p) {
      const int k = kr + p * 64;
      float4 v = *(const float4*)(Bsrc + (size_t)k * 512 + n0 + c4);
      const float vf[4] = {v.x, v.y, v.z, v.w};
      const int kc = k >> 3, klo = k & 7;
#pragma unroll
      for (int q = 0; q < 4; ++q) {
        const int n = c4 + q;
        unsigned u = __float_as_uint(vf[q]);
        unsigned hb = u & 0xffff0000u;
        float lo = vf[q] - __uint_as_float(hb);
        const int slot = (kc & ~7) | ((kc ^ n) & 7);
        BT[0][n][slot * 8 + klo] = (short)(hb >> 16);
        BT[1][n][slot * 8 + klo] = (short)(__float_as_uint(lo) >> 16);
      }
    }
  }
  __syncthreads();
  // ---- zero-barrier K-loop ----
  const int w = tid >> 6, lane = tid & 63;
  const int fm = lane & 15, fc = lane >> 4;       // A row / k-chunk
  const float* Ap = Asrc + (size_t)(w * 16 + fm) * 512 + fc * 8;
  f32x4 acc0 = {}, acc1 = {};
  float4 fa = *(const float4*)(Ap);
  float4 fb = *(const float4*)(Ap + 4);
  for (int it = 0; it < 16; ++it) {
    float4 na, nb;
    if (it < 15) {
      na = *(const float4*)(Ap + (it + 1) * 32);
      nb = *(const float4*)(Ap + (it + 1) * 32 + 4);
    }
    const float af[8] = {fa.x, fa.y, fa.z, fa.w, fb.x, fb.y, fb.z, fb.w};
    short8v ah, al;
#pragma unroll
    for (int e = 0; e < 8; ++e) {
      unsigned u = __float_as_uint(af[e]);
      unsigned hb = u & 0xffff0000u;
      ah[e] = (short)(hb >> 16);
      al[e] = (short)(__float_as_uint(af[e] - __uint_as_float(hb)) >> 16);
    }
    const int kc = it * 4 + fc;
    const int base = kc & ~7;
    const int s0 = (base | ((kc ^ fm) & 7)) * 8;
    const int s1 = (base | ((kc ^ (16 + fm)) & 7)) * 8;
    short8v bh0 = *(const short8v*)&BT[0][fm][s0];
    short8v bl0 = *(const short8v*)&BT[1][fm][s0];
    short8v bh1 = *(const short8v*)&BT[0][16 + fm][s1];
    short8v bl1 = *(const short8v*)&BT[1][16 + fm][s1];
    acc0 = __builtin_amdgcn_mfma_f32_16x16x32_bf16(ah, bh0, acc0, 0, 0, 0);
    acc1 = __builtin_amdgcn_mfma_f32_16x16x32_bf16(ah, bh1, acc1, 0, 0, 0);
    acc0 = __builtin_amdgcn_mfma_f32_16x16x32_bf16(ah, bl0, acc0, 0, 0, 0);
    acc1 = __builtin_amdgcn_mfma_f32_16x16x32_bf16(ah, bl1, acc1, 0, 0, 0);
    acc0 = __builtin_amdgcn_mfma_f32_16x16x32_bf16(al, bh0, acc0, 0, 0, 0);
    acc1 = __builtin_amdgcn_mfma_f32_16x16x32_bf16(al, bh1, acc1, 0, 0, 0);
    fa = na; fb = nb;
  }
  const int row = m0 + w * 16 + fc * 4;
  float* Cp = C + (size_t)row * 512 + n0 + fm;
#pragma unroll
  for (int r = 0; r < 4; ++r) Cp[(size_t)r * 512] = acc0[r];
#pragma unroll
  for (int r = 0; r < 4; ++r) Cp[(size_t)r * 512 + 16] = acc1[r];
}

// ---- attn_fused: 4 d's share each Ws element; factored exp (1 exp + 4 rcp) ----
#define C2 2.8853900817779268f   // 2*log2(e)
__global__ __launch_bounds__(512) void attn_fused(
    const float* __restrict__ Ws, const float* __restrict__ Uh,
    const float* __restrict__ Va, const float* __restrict__ enc,
    float* __restrict__ c_out, float* __restrict__ e_out) {
  __shared__ float sUh[4][HE_];
  __shared__ float sV[HE_];
  __shared__ float sE[4][TE_];
  __shared__ float sNorm[4];
  const int tid = threadIdx.x;
  const int b  = blockIdx.x & 7;          // XCD-aligned b partition
  const int d0 = (blockIdx.x >> 3) * 4;
  ((float4*)sUh)[tid] = ((const float4*)(Uh + (size_t)(b * TD_ + d0) * HE_))[tid];
  if (tid < 128) ((float4*)sV)[tid] = ((const float4*)Va)[tid];
  __syncthreads();
  const int lane = tid & 63, w = tid >> 6;
  const int tb = w * 32;                  // 32 t per wave, all 4 d
  const int h0 = lane * 8;
  float eU[4][8], vv2[8], sumv = 0.f;
#pragma unroll
  for (int j = 0; j < 8; ++j) {
    const float vj = sV[h0 + j];
    sumv += vj;
    vv2[j] = 2.0f * vj;
#pragma unroll
    for (int d = 0; d < 4; ++d)
      eU[d][j] = __builtin_amdgcn_exp2f(C2 * sUh[d][h0 + j]);
  }
  const float* pw = Ws + ((size_t)b * TE_ + tb) * HE_ + h0;
  float4 a0 = *(const float4*)(pw);
  float4 a1 = *(const float4*)(pw + 4);
  float s0, s1, s2, s3;
#define TELT4(X, J) { \
    float EW = __builtin_amdgcn_exp2f(C2 * (X)); \
    float E0 = EW * eU[0][J], E1 = EW * eU[1][J]; \
    float E2 = EW * eU[2][J], E3 = EW * eU[3][J]; \
    float r0 = __builtin_amdgcn_rcpf(E0 + 1.0f); \
    float r1 = __builtin_amdgcn_rcpf(E1 + 1.0f); \
    float r2 = __builtin_amdgcn_rcpf(E2 + 1.0f); \
    float r3 = __builtin_amdgcn_rcpf(E3 + 1.0f); \
    s0 = fmaf(-vv2[J], r0, s0); s1 = fmaf(-vv2[J], r1, s1); \
    s2 = fmaf(-vv2[J], r2, s2); s3 = fmaf(-vv2[J], r3, s3); }
  for (int ti = 0; ti < 32; ++ti) {
    const float* pn = pw + HE_;
    float4 n0 = *(const float4*)(pn);       // prefetch (OOB-safe: next row exists)
    float4 n1 = *(const float4*)(pn + 4);
    s0 = s1 = s2 = s3 = sumv;
    TELT4(a0.x, 0) TELT4(a0.y, 1) TELT4(a0.z, 2) TELT4(a0.w, 3)
    TELT4(a1.x, 4) TELT4(a1.y, 5) TELT4(a1.z, 6) TELT4(a1.w, 7)
#pragma unroll
    for (int off = 32; off; off >>= 1) {
      s0 += __shfl_down(s0, off, 64);
      s1 += __shfl_down(s1, off, 64);
      s2 += __shfl_down(s2, off, 64);
      s3 += __shfl_down(s3, off, 64);
    }
    if (lane == 0) {
      sE[0][tb + ti] = s0; sE[1][tb + ti] = s1;
      sE[2][tb + ti] = s2; sE[3][tb + ti] = s3;
    }
    a0 = n0; a1 = n1;
    pw = pn;
  }
  __syncthreads();
  // softmax (no max-subtraction: |logit| <= sum|V| ~ 21, exp safe in fp32)
  const int dA = tid >> 8, t = tid & 255;
  const float ex0 = __expf(sE[dA][t]);
  const float ex1 = __expf(sE[2 + dA][t]);
  sE[dA][t] = ex0;
  sE[2 + dA][t] = ex1;
  __syncthreads();
  if (w < 4) {
    float s = sE[w][lane] + sE[w][lane + 64] + sE[w][lane + 128] + sE[w][lane + 192];
#pragma unroll
    for (int off = 32; off; off >>= 1) s += __shfl_down(s, off, 64);
    if (lane == 0) sNorm[w] = 1.0f / s;
  }
  __syncthreads();
  const float w0 = ex0 * sNorm[dA];
  const float w1 = ex1 * sNorm[2 + dA];
  sE[dA][t] = w0;
  sE[2 + dA][t] = w1;
  e_out[(size_t)(b * TD_ + d0 + dA) * TE_ + t] = w0;
  e_out[(size_t)(b * TD_ + d0 + 2 + dA) * TE_ + t] = w1;
  __syncthreads();
  // phase 3: thread owns h = tid, 4 d-accumulators
  float a0c = 0.f, a1c = 0.f, a2c = 0.f, a3c = 0.f;
  const float* ep = enc + (size_t)b * TE_ * HE_ + tid;
#pragma unroll 4
  for (int tt = 0; tt < TE_; ++tt) {
    const float ev = ep[(size_t)tt * HE_];
    a0c = fmaf(sE[0][tt], ev, a0c);
    a1c = fmaf(sE[1][tt], ev, a1c);
    a2c = fmaf(sE[2][tt], ev, a2c);
    a3c = fmaf(sE[3][tt], ev, a3c);
  }
  float* cp = c_out + (size_t)(b * TD_ + d0) * HE_ + tid;
  cp[0]        = a0c;
  cp[HE_]      = a1c;
  cp[2 * HE_]  = a2c;
  cp[3 * HE_]  = a3c;
}

extern "C" void kernel_launch(void* const* d_in, const int* in_sizes, int n_in,
                              void* d_out, int out_size, void* d_ws, size_t ws_size,
                              hipStream_t stream) {
  const float* enc = (const float*)d_in[0];   // [8,256,512]
  const float* dec = (const float*)d_in[1];   // [8,128,512]
  const float* Wa  = (const float*)d_in[2];   // [512,512]
  const float* Ua  = (const float*)d_in[3];   // [512,512]
  const float* Va  = (const float*)d_in[4];   // [512,1]
  float* c_out = (float*)d_out;
  float* e_out = c_out + (size_t)B_ * TD_ * HE_;
  float* Cws = (float*)d_ws;                  // [3072,512] fp32 = 6 MB
  const float* Ws = Cws;                      // rows 0..2047
  const float* Uh = Cws + (size_t)2048 * 512; // rows 2048..3071
  gemm_fused<<<384, 512, 0, stream>>>(enc, dec, Wa, Ua, Cws);
  attn_fused<<<256, 512, 0, stream>>>(Ws, Uh, Va, enc, c_out, e_out);
}